// Round 2
// baseline (869.622 us; speedup 1.0000x reference)
//
#include <hip/hip_runtime.h>

// gamma[i] = || (e0 + G e0 + G^2 e0 + G^3 e0 + G^4 e0)/5 [drugs[i]] ||^2
// Strategy: build CSR on device (hist + scan + counting-sort scatter), then
// 4 pull-based SpMM passes (wave per row, lane per dim, coalesced 256B row
// gathers, no float atomics). Drug rows accumulated into a small buffer.

__global__ __launch_bounds__(256) void hist_kernel(const int* __restrict__ row,
                                                   int* __restrict__ cnt, int E) {
    int stride = gridDim.x * blockDim.x;
    for (int e = blockIdx.x * blockDim.x + threadIdx.x; e < E; e += stride)
        atomicAdd(&cnt[row[e]], 1);
}

// pass1: per-block (1024-elem chunk) sums
__global__ __launch_bounds__(256) void scan1_kernel(const int* __restrict__ cnt,
                                                    int* __restrict__ partial, int N) {
    __shared__ int sdata[256];
    int base = blockIdx.x * 1024;
    int t = threadIdx.x;
    int sum = 0;
#pragma unroll
    for (int j = 0; j < 4; ++j) {
        int idx = base + j * 256 + t;
        if (idx < N) sum += cnt[idx];
    }
    sdata[t] = sum;
    __syncthreads();
    for (int d = 128; d > 0; d >>= 1) {
        if (t < d) sdata[t] += sdata[t + d];
        __syncthreads();
    }
    if (t == 0) partial[blockIdx.x] = sdata[0];
}

// pass2: exclusive scan of block sums (nblk <= 256), write total into *offN
__global__ __launch_bounds__(256) void scan2_kernel(int* __restrict__ partial, int nblk,
                                                    int* __restrict__ offN) {
    __shared__ int sdata[256];
    int t = threadIdx.x;
    int v = (t < nblk) ? partial[t] : 0;
    sdata[t] = v;
    __syncthreads();
    for (int d = 1; d < 256; d <<= 1) {
        int tmp = (t >= d) ? sdata[t - d] : 0;
        __syncthreads();
        sdata[t] += tmp;
        __syncthreads();
    }
    int incl = sdata[t];
    if (t < nblk) partial[t] = incl - v;  // exclusive
    if (t == 255) *offN = incl;           // total = E
}

// pass3: block exclusive scan of chunk; write off[] (row starts) and cursor copy
__global__ __launch_bounds__(256) void scan3_kernel(int* __restrict__ cnt /*in counts, out cursor*/,
                                                    const int* __restrict__ partial,
                                                    int* __restrict__ off, int N) {
    __shared__ int sdata[256];
    int base = blockIdx.x * 1024;
    int t = threadIdx.x;
    int v[4];
    int sum = 0;
#pragma unroll
    for (int j = 0; j < 4; ++j) {
        int idx = base + t * 4 + j;
        v[j] = (idx < N) ? cnt[idx] : 0;
        sum += v[j];
    }
    sdata[t] = sum;
    __syncthreads();
    for (int d = 1; d < 256; d <<= 1) {
        int tmp = (t >= d) ? sdata[t - d] : 0;
        __syncthreads();
        sdata[t] += tmp;
        __syncthreads();
    }
    int excl = sdata[t] - sum + partial[blockIdx.x];
#pragma unroll
    for (int j = 0; j < 4; ++j) {
        int idx = base + t * 4 + j;
        if (idx < N) { off[idx] = excl; cnt[idx] = excl; }
        excl += v[j];
    }
}

// counting-sort scatter of (col, val) into row-grouped int2 array
__global__ __launch_bounds__(256) void scatter_kernel(const int* __restrict__ row,
                                                      const int* __restrict__ col,
                                                      const float* __restrict__ val,
                                                      int* __restrict__ cursor,
                                                      int2* __restrict__ edges, int E) {
    int stride = gridDim.x * blockDim.x;
    for (int e = blockIdx.x * blockDim.x + threadIdx.x; e < E; e += stride) {
        int r = row[e];
        int p = atomicAdd(&cursor[r], 1);
        edges[p] = make_int2(col[e], __float_as_int(val[e]));
    }
}

// pull SpMM: one wave per row, lane = dim. y[r] = sum val * x[col]
__global__ __launch_bounds__(256) void spmm_kernel(const float* __restrict__ x,
                                                   float* __restrict__ y,
                                                   const int* __restrict__ off,
                                                   const int2* __restrict__ edges, int N) {
    int w = (blockIdx.x * 256 + threadIdx.x) >> 6;
    int lane = threadIdx.x & 63;
    if (w >= N) return;
    int s = off[w], e = off[w + 1];
    float a0 = 0.f, a1 = 0.f, a2 = 0.f, a3 = 0.f;
    int i = s;
    for (; i + 4 <= e; i += 4) {
        int2 m0 = edges[i], m1 = edges[i + 1], m2 = edges[i + 2], m3 = edges[i + 3];
        a0 += __int_as_float(m0.y) * x[(size_t)m0.x * 64 + lane];
        a1 += __int_as_float(m1.y) * x[(size_t)m1.x * 64 + lane];
        a2 += __int_as_float(m2.y) * x[(size_t)m2.x * 64 + lane];
        a3 += __int_as_float(m3.y) * x[(size_t)m3.x * 64 + lane];
    }
    for (; i < e; ++i) {
        int2 m = edges[i];
        a0 += __int_as_float(m.y) * x[(size_t)m.x * 64 + lane];
    }
    y[(size_t)w * 64 + lane] = (a0 + a1) + (a2 + a3);
}

__global__ __launch_bounds__(256) void gather_init_kernel(float* __restrict__ sacc,
                                                          const float* __restrict__ src,
                                                          const int* __restrict__ drugs, int B) {
    int idx = blockIdx.x * 256 + threadIdx.x;
    if (idx >= B * 64) return;
    int i = idx >> 6, d = idx & 63;
    sacc[idx] = src[(size_t)drugs[i] * 64 + d];
}

__global__ __launch_bounds__(256) void gather_add_kernel(float* __restrict__ sacc,
                                                         const float* __restrict__ src,
                                                         const int* __restrict__ drugs, int B) {
    int idx = blockIdx.x * 256 + threadIdx.x;
    if (idx >= B * 64) return;
    int i = idx >> 6, d = idx & 63;
    sacc[idx] += src[(size_t)drugs[i] * 64 + d];
}

// gamma[i] = || sacc[i] * 0.2 ||^2  (wave per drug row)
__global__ __launch_bounds__(256) void gamma_kernel(const float* __restrict__ sacc,
                                                    float* __restrict__ out, int B) {
    int w = (blockIdx.x * 256 + threadIdx.x) >> 6;
    int lane = threadIdx.x & 63;
    if (w >= B) return;
    float v = sacc[(size_t)w * 64 + lane] * 0.2f;
    v = v * v;
    for (int o = 32; o > 0; o >>= 1) v += __shfl_down(v, o, 64);
    if (lane == 0) out[w] = v;
}

extern "C" void kernel_launch(void* const* d_in, const int* in_sizes, int n_in,
                              void* d_out, int out_size, void* d_ws, size_t ws_size,
                              hipStream_t stream) {
    (void)n_in; (void)ws_size;
    const float* emb       = (const float*)d_in[0];
    const float* edge_vals = (const float*)d_in[1];
    const int*   edge_row  = (const int*)d_in[2];
    const int*   edge_col  = (const int*)d_in[3];
    const int*   drugs     = (const int*)d_in[4];
    int N = in_sizes[0] / 64;
    int E = in_sizes[1];
    int B = in_sizes[4];
    float* gamma_out = (float*)d_out;
    (void)out_size;

    char* ws = (char*)d_ws;
    size_t o = 0;
    auto alloc = [&](size_t bytes) -> void* {
        o = (o + 255) & ~(size_t)255;
        void* p = ws + o;
        o += bytes;
        return p;
    };
    int*   cnt     = (int*)alloc((size_t)N * 4);            // counts -> cursor
    int*   off     = (int*)alloc((size_t)(N + 1) * 4);      // CSR row starts
    int*   partial = (int*)alloc(4096);                     // scan block sums
    int2*  edges   = (int2*)alloc((size_t)E * 8);           // (col, val) sorted by row
    float* bufA    = (float*)alloc((size_t)N * 64 * 4);
    float* bufB    = (float*)alloc((size_t)N * 64 * 4);
    float* sacc    = (float*)alloc((size_t)B * 64 * 4);

    // ---- CSR build ----
    hipMemsetAsync(cnt, 0, (size_t)N * 4, stream);
    hist_kernel<<<2048, 256, 0, stream>>>(edge_row, cnt, E);
    int nblk = (N + 1023) / 1024;
    scan1_kernel<<<nblk, 256, 0, stream>>>(cnt, partial, N);
    scan2_kernel<<<1, 256, 0, stream>>>(partial, nblk, off + N);
    scan3_kernel<<<nblk, 256, 0, stream>>>(cnt, partial, off, N);
    scatter_kernel<<<2048, 256, 0, stream>>>(edge_row, edge_col, edge_vals, cnt, edges, E);

    // ---- 5-term LightGCN-ODE sum over drug rows ----
    int gatherGrid = (B * 64 + 255) / 256;
    gather_init_kernel<<<gatherGrid, 256, 0, stream>>>(sacc, emb, drugs, B);

    int spmmGrid = (N + 3) / 4;
    spmm_kernel<<<spmmGrid, 256, 0, stream>>>(emb, bufA, off, edges, N);   // G e0
    gather_add_kernel<<<gatherGrid, 256, 0, stream>>>(sacc, bufA, drugs, B);
    spmm_kernel<<<spmmGrid, 256, 0, stream>>>(bufA, bufB, off, edges, N);  // G^2 e0
    gather_add_kernel<<<gatherGrid, 256, 0, stream>>>(sacc, bufB, drugs, B);
    spmm_kernel<<<spmmGrid, 256, 0, stream>>>(bufB, bufA, off, edges, N);  // G^3 e0
    gather_add_kernel<<<gatherGrid, 256, 0, stream>>>(sacc, bufA, drugs, B);
    spmm_kernel<<<spmmGrid, 256, 0, stream>>>(bufA, bufB, off, edges, N);  // G^4 e0
    gather_add_kernel<<<gatherGrid, 256, 0, stream>>>(sacc, bufB, drugs, B);

    gamma_kernel<<<(B + 3) / 4, 256, 0, stream>>>(sacc, gamma_out, B);
}